// Round 10
// baseline (442.598 us; speedup 1.0000x reference)
//
#include <hip/hip_runtime.h>
#include <math.h>

#define N_NODES 20000
#define M_NEI   32
#define DIM     256
#define H_HEADS 4
#define D_HEAD  64
#define LN_EPS  1e-5f
#define NEG_INF -1.0e9f
#define APAD    264         // 256 + 8 halves pad for LDS A tile
#define NB      4           // nodes per k_fuse block
#define NBLK_G  625         // k_gemm tiles
#define NBLK_F  5000        // k_fuse blocks
#define REPL_G  6           // probe replication factors (measurement round)
#define REPL_F  3
#define REPL_P1 8
#define REPL_P2 4

using short8  = __attribute__((ext_vector_type(8))) short;
using short4v = __attribute__((ext_vector_type(4))) short;
using floatx4 = __attribute__((ext_vector_type(4))) float;
using floatx2 = __attribute__((ext_vector_type(2))) float;
using uintx4  = __attribute__((ext_vector_type(4))) unsigned int;
using uintx2  = __attribute__((ext_vector_type(2))) unsigned int;

__device__ __forceinline__ float bf2f(unsigned short u) {
    union { unsigned int i; float f; } c; c.i = ((unsigned int)u) << 16; return c.f;
}
__device__ __forceinline__ float u2f(unsigned int i) {
    union { unsigned int i; float f; } c; c.i = i; return c.f;
}
__device__ __forceinline__ unsigned short f2bf(float f) {
    union { float f; unsigned int i; } c; c.f = f;
    unsigned int x = c.i;
    x += 0x7fffu + ((x >> 16) & 1u);          // RNE
    return (unsigned short)(x >> 16);
}
__device__ __forceinline__ bool in_is_fp32(const void* gamma) {
    return *(const unsigned int*)gamma == 0x3F800000u;
}
__device__ __forceinline__ float fast_exp(float x) {
    return __builtin_amdgcn_exp2f(x * 1.44269504088896341f);
}
// A&S 7.1.26 erf (max abs err 1.5e-7); invisible at bf16 output precision.
__device__ __forceinline__ float erf_fast(float x) {
    float ax = fabsf(x);
    float t  = __builtin_amdgcn_rcpf(fmaf(0.3275911f, ax, 1.0f));
    float p  = fmaf(1.061405429f, t, -1.453152027f);
    p = fmaf(p, t, 1.421413741f);
    p = fmaf(p, t, -0.284496736f);
    p = fmaf(p, t, 0.254829592f);
    p = p * t;
    float e  = __builtin_amdgcn_exp2f(-ax * ax * 1.44269504088896341f);
    float r  = fmaf(-p, e, 1.0f);
    return copysignf(r, x);
}

// ---------------- GEMM (real, x6 replicated: replicas write identical bytes) ---
__global__ __launch_bounds__(256, 2) void k_gemm(const void* __restrict__ A,
                                                 const void* __restrict__ gamma,
                                                 const void* __restrict__ W,
                                                 const void* __restrict__ al,
                                                 const void* __restrict__ ar,
                                                 unsigned short* __restrict__ hp,
                                                 float* __restrict__ el_nh,
                                                 float* __restrict__ er_nh) {
    __shared__ unsigned short sA[32][APAD];
    const bool f32 = in_is_fp32(gamma);
    const int t    = threadIdx.x;
    const int m0   = (blockIdx.x % NBLK_G) * 32;   // replica remap (prologue only)
    const int hd   = t >> 6;
    const int lane = t & 63;
    const int r    = lane & 15;
    const int quad = lane >> 4;
    const int n0   = hd * 64;

    short8 breg[4][8];
    if (f32) {
        #pragma unroll
        for (int c = 0; c < 4; ++c) {
            const float* wp = (const float*)W + (size_t)quad * 8 * DIM + n0 + c * 16 + r;
            #pragma unroll
            for (int kq = 0; kq < 8; ++kq) {
                #pragma unroll
                for (int j = 0; j < 8; ++j)
                    breg[c][kq][j] = (short)f2bf(wp[(size_t)(kq * 32 + j) * DIM]);
            }
        }
    } else {
        #pragma unroll
        for (int c = 0; c < 4; ++c) {
            const unsigned short* wp = (const unsigned short*)W + (size_t)quad * 8 * DIM + n0 + c * 16 + r;
            #pragma unroll
            for (int kq = 0; kq < 8; ++kq) {
                #pragma unroll
                for (int j = 0; j < 8; ++j)
                    breg[c][kq][j] = (short)wp[(size_t)(kq * 32 + j) * DIM];
            }
        }
    }

    #pragma unroll
    for (int it = 0; it < 4; ++it) {
        int chunk = it * 256 + t;
        int row   = chunk >> 5;
        int c16   = chunk & 31;
        short8 v;
        if (!f32) {
            v = *(const short8*)((const unsigned short*)A + (size_t)(m0 + row) * DIM + c16 * 8);
        } else {
            const float* ap = (const float*)A + (size_t)(m0 + row) * DIM + c16 * 8;
            floatx4 f0 = *(const floatx4*)ap;
            floatx4 f1 = *(const floatx4*)(ap + 4);
            #pragma unroll
            for (int j = 0; j < 4; ++j) {
                v[j]     = (short)f2bf(f0[j]);
                v[4 + j] = (short)f2bf(f1[j]);
            }
        }
        *(short8*)&sA[row][c16 * 8] = v;
    }
    __syncthreads();

    floatx4 acc[2][4];
    #pragma unroll
    for (int rf = 0; rf < 2; ++rf)
        #pragma unroll
        for (int c = 0; c < 4; ++c) acc[rf][c] = (floatx4){0.f, 0.f, 0.f, 0.f};

    #pragma unroll
    for (int kq = 0; kq < 8; ++kq) {
        short8 a0 = *(const short8*)&sA[r][kq * 32 + quad * 8];
        short8 a1 = *(const short8*)&sA[16 + r][kq * 32 + quad * 8];
        #pragma unroll
        for (int c = 0; c < 4; ++c) {
            acc[0][c] = __builtin_amdgcn_mfma_f32_16x16x32_bf16(a0, breg[c][kq], acc[0][c], 0, 0, 0);
            acc[1][c] = __builtin_amdgcn_mfma_f32_16x16x32_bf16(a1, breg[c][kq], acc[1][c], 0, 0, 0);
        }
    }

    float alv[4], arv[4];
    #pragma unroll
    for (int c = 0; c < 4; ++c) {
        int col = n0 + c * 16 + r;
        if (f32) { alv[c] = ((const float*)al)[col]; arv[c] = ((const float*)ar)[col]; }
        else     { alv[c] = bf2f(((const unsigned short*)al)[col]);
                   arv[c] = bf2f(((const unsigned short*)ar)[col]); }
    }

    #pragma unroll
    for (int rf = 0; rf < 2; ++rf) {
        #pragma unroll
        for (int rr = 0; rr < 4; ++rr) {
            const int row = m0 + rf * 16 + quad * 4 + rr;
            float sl = 0.f, sr = 0.f;
            #pragma unroll
            for (int c = 0; c < 4; ++c) {
                float v = acc[rf][c][rr];
                sl += v * alv[c];
                sr += v * arv[c];
                hp[(size_t)row * DIM + n0 + c * 16 + r] = f2bf(v);
            }
            #pragma unroll
            for (int off = 1; off < 16; off <<= 1) {
                sl += __shfl_xor(sl, off);
                sr += __shfl_xor(sr, off);
            }
            if (r == 0) {
                el_nh[(size_t)row * H_HEADS + hd] = sl;
                er_nh[(size_t)row * H_HEADS + hd] = sr;
            }
        }
    }
}

// ---------------- PROBE k_p1: phase 1 only (softmax + compaction) ---------------
// x8 replicated; stores LDS results to out (garbage, overwritten by real k_fuse).
__global__ __launch_bounds__(256) void k_p1(const int* __restrict__ nidx,
                                            const int* __restrict__ nmask,
                                            const float* __restrict__ el_nh,
                                            const float* __restrict__ er_nh,
                                            void* __restrict__ out) {
    __shared__ int   s_off[NB][33];
    __shared__ float s_al[NB][33][4];
    __shared__ int   s_cnt[NB];

    const int t   = threadIdx.x;
    const int nb0 = (blockIdx.x % NBLK_F) * NB;

    {
        int*     offp = &s_off[0][0];
        floatx4* alp  = (floatx4*)&s_al[0][0][0];
        if (t < NB * 33) {
            offp[t] = 0;
            alp[t]  = (floatx4){0.f, 0.f, 0.f, 0.f};
        }
    }
    __syncthreads();

    if (t < NB * 32) {
        const int m   = t & 31;
        const int nl  = t >> 5;
        const int n   = nb0 + nl;
        const int idx = nidx[(size_t)n * M_NEI + m];
        const int msk = nmask[(size_t)n * M_NEI + m];
        floatx4 el4 = *(const floatx4*)(el_nh + (size_t)n * H_HEADS);
        floatx4 er4 = *(const floatx4*)(er_nh + (size_t)idx * H_HEADS);
        floatx4 e4, a4;
        #pragma unroll
        for (int hh = 0; hh < 4; ++hh) {
            float e = el4[hh] + er4[hh];
            e = (e > 0.f) ? e : 0.2f * e;
            e4[hh] = msk ? e : NEG_INF;
        }
        floatx4 mx = e4;
        #pragma unroll
        for (int off = 1; off < 32; off <<= 1)
            #pragma unroll
            for (int hh = 0; hh < 4; ++hh)
                mx[hh] = fmaxf(mx[hh], __shfl_xor(mx[hh], off, 32));
        #pragma unroll
        for (int hh = 0; hh < 4; ++hh) a4[hh] = fast_exp(e4[hh] - mx[hh]);
        floatx4 sm = a4;
        #pragma unroll
        for (int off = 1; off < 32; off <<= 1)
            #pragma unroll
            for (int hh = 0; hh < 4; ++hh)
                sm[hh] += __shfl_xor(sm[hh], off, 32);
        #pragma unroll
        for (int hh = 0; hh < 4; ++hh) a4[hh] *= __builtin_amdgcn_rcpf(sm[hh]);

        unsigned long long bal64 = __ballot(msk != 0);
        unsigned int bal = (t & 32) ? (unsigned int)(bal64 >> 32)
                                    : (unsigned int)bal64;
        int  cnt   = __popc(bal);
        bool valid = (msk != 0);
        if (cnt == 0) { valid = true; cnt = 32; bal = 0xffffffffu; }
        if (valid) {
            int pfx = __popc(bal & ((1u << m) - 1u));
            s_off[nl][pfx] = idx * (DIM * 2);
            *(floatx4*)&s_al[nl][pfx][0] = a4;
        }
        if (m == 0) s_cnt[nl] = cnt;
    }
    __syncthreads();

    // keep results live: garbage store into out (fully overwritten by real k_fuse)
    if (t < NB * 32) {
        const int nl = t >> 5, m = t & 31;
        float v = s_al[nl][m][0] + (float)s_off[nl][m] + (float)s_cnt[nl];
        ((float*)out)[((blockIdx.x & 1023) * 128 + t)] = v;   // < 512KB, in-bounds
    }
}

// ---------------- PROBE k_p2: phase 2 only, synthetic offsets -------------------
// mode=0: hash-random rows (matches real gather address pattern, cnt=20).
// mode=1: node-own row every slot (cache-hot) — same code, only LDS contents
// differ. Delta isolates random-gather latency/BW from VALU+LDS core cost.
__global__ __launch_bounds__(256) void k_p2(const unsigned short* __restrict__ hp,
                                            const void* __restrict__ gamma,
                                            const void* __restrict__ beta,
                                            void* __restrict__ out,
                                            int mode) {
    __shared__ int   s_off[NB][33];
    __shared__ float s_al[NB][33][4];
    __shared__ int   s_cnt[NB];

    const int t   = threadIdx.x;
    const int nb0 = (blockIdx.x % NBLK_F) * NB;

    if (t < NB * 33) {
        const int nl   = t / 33;
        const int slot = t % 33;
        const int n    = nb0 + nl;
        unsigned hsh = (unsigned)(n * 33 + slot) * 2654435761u;
        int idx = (int)(((unsigned long long)hsh * N_NODES) >> 32);
        s_off[nl][slot] = (mode ? n : idx) * (DIM * 2);
        *(floatx4*)&s_al[nl][slot][0] = (floatx4){0.03f, 0.03f, 0.03f, 0.03f};
        if (slot == 0) s_cnt[nl] = 20;
    }
    __syncthreads();

    // ---- phase 2 verbatim from k_fuse ----
    const bool f32 = in_is_fp32(gamma);
    const int nl   = t >> 6;
    const int lane = t & 63;
    const int hq   = lane >> 4;
    const int n    = nb0 + nl;
    const int cnt  = s_cnt[nl];
    const char* tbl = (const char*)hp + (size_t)lane * 8;

    float gv[4], bv[4];
    if (f32) {
        #pragma unroll
        for (int i = 0; i < 4; ++i) {
            gv[i] = ((const float*)gamma)[lane * 4 + i];
            bv[i] = ((const float*)beta)[lane * 4 + i];
        }
    } else {
        #pragma unroll
        for (int i = 0; i < 4; ++i) {
            gv[i] = bf2f(((const unsigned short*)gamma)[lane * 4 + i]);
            bv[i] = bf2f(((const unsigned short*)beta)[lane * 4 + i]);
        }
    }

    floatx2 acc[2];
    acc[0] = (floatx2){0.f, 0.f};
    acc[1] = (floatx2){0.f, 0.f};

    for (int m = 0; m < cnt; m += 4) {
        #pragma unroll
        for (int k = 0; k < 4; ++k) {
            const int   off = s_off[nl][m + k];
            const float aa  = s_al[nl][m + k][hq];
            uintx2 u = *(const uintx2*)(tbl + off);
            #pragma unroll
            for (int j = 0; j < 2; ++j) {
                floatx2 f = { u2f(u[j] << 16), u2f(u[j] & 0xffff0000u) };
                acc[j] += (floatx2){aa, aa} * f;
            }
        }
    }
    {
        uintx2 u = *(const uintx2*)((const char*)hp + (size_t)n * (DIM * 2) + lane * 8);
        #pragma unroll
        for (int j = 0; j < 2; ++j) {
            floatx2 f = { u2f(u[j] << 16), u2f(u[j] & 0xffff0000u) };
            acc[j] += f;
        }
    }

    float x[4], s1 = 0.f, s2 = 0.f;
    #pragma unroll
    for (int j = 0; j < 2; ++j) {
        #pragma unroll
        for (int e = 0; e < 2; ++e) {
            float xi = acc[j][e];
            xi = 0.5f * xi * (1.f + erf_fast(xi * 0.70710678118654752f));
            x[2 * j + e] = xi;
            s1 += xi;
            s2 += xi * xi;
        }
    }
    #pragma unroll
    for (int off = 1; off < 64; off <<= 1) {
        s1 += __shfl_xor(s1, off);
        s2 += __shfl_xor(s2, off);
    }
    const float mu  = s1 * (1.f / 256.f);
    float var = s2 * (1.f / 256.f) - mu * mu;
    var = fmaxf(var, 0.f);
    const float inv = rsqrtf(var + LN_EPS);

    if (f32) {
        floatx4 o;
        #pragma unroll
        for (int i = 0; i < 4; ++i)
            o[i] = (x[i] - mu) * inv * gv[i] + bv[i];
        *(floatx4*)((float*)out + (size_t)n * DIM + lane * 4) = o;   // garbage; overwritten
    } else {
        short4v o;
        #pragma unroll
        for (int i = 0; i < 4; ++i)
            o[i] = (short)f2bf((x[i] - mu) * inv * gv[i] + bv[i]);
        *(short4v*)((unsigned short*)out + (size_t)n * DIM + lane * 4) = o;
    }
}

// ---------------- fused attention (real, x3 replicated, launched LAST) ----------
__global__ __launch_bounds__(256) void k_fuse(const int* __restrict__ nidx,
                                              const int* __restrict__ nmask,
                                              const unsigned short* __restrict__ hp,
                                              const float* __restrict__ el_nh,
                                              const float* __restrict__ er_nh,
                                              const void* __restrict__ gamma,
                                              const void* __restrict__ beta,
                                              void* __restrict__ out) {
    __shared__ int   s_off[NB][33];
    __shared__ float s_al[NB][33][4];
    __shared__ int   s_cnt[NB];

    const int t   = threadIdx.x;
    const int nb0 = (blockIdx.x % NBLK_F) * NB;   // replica remap

    {
        int*     offp = &s_off[0][0];
        floatx4* alp  = (floatx4*)&s_al[0][0][0];
        if (t < NB * 33) {
            offp[t] = 0;
            alp[t]  = (floatx4){0.f, 0.f, 0.f, 0.f};
        }
    }
    __syncthreads();

    if (t < NB * 32) {
        const int m   = t & 31;
        const int nl  = t >> 5;
        const int n   = nb0 + nl;
        const int idx = nidx[(size_t)n * M_NEI + m];
        const int msk = nmask[(size_t)n * M_NEI + m];
        floatx4 el4 = *(const floatx4*)(el_nh + (size_t)n * H_HEADS);
        floatx4 er4 = *(const floatx4*)(er_nh + (size_t)idx * H_HEADS);
        floatx4 e4, a4;
        #pragma unroll
        for (int hh = 0; hh < 4; ++hh) {
            float e = el4[hh] + er4[hh];
            e = (e > 0.f) ? e : 0.2f * e;
            e4[hh] = msk ? e : NEG_INF;
        }
        floatx4 mx = e4;
        #pragma unroll
        for (int off = 1; off < 32; off <<= 1)
            #pragma unroll
            for (int hh = 0; hh < 4; ++hh)
                mx[hh] = fmaxf(mx[hh], __shfl_xor(mx[hh], off, 32));
        #pragma unroll
        for (int hh = 0; hh < 4; ++hh) a4[hh] = fast_exp(e4[hh] - mx[hh]);
        floatx4 sm = a4;
        #pragma unroll
        for (int off = 1; off < 32; off <<= 1)
            #pragma unroll
            for (int hh = 0; hh < 4; ++hh)
                sm[hh] += __shfl_xor(sm[hh], off, 32);
        #pragma unroll
        for (int hh = 0; hh < 4; ++hh) a4[hh] *= __builtin_amdgcn_rcpf(sm[hh]);

        unsigned long long bal64 = __ballot(msk != 0);
        unsigned int bal = (t & 32) ? (unsigned int)(bal64 >> 32)
                                    : (unsigned int)bal64;
        int  cnt   = __popc(bal);
        bool valid = (msk != 0);
        if (cnt == 0) { valid = true; cnt = 32; bal = 0xffffffffu; }
        if (valid) {
            int pfx = __popc(bal & ((1u << m) - 1u));
            s_off[nl][pfx] = idx * (DIM * 2);
            *(floatx4*)&s_al[nl][pfx][0] = a4;
        }
        if (m == 0) s_cnt[nl] = cnt;
    }
    __syncthreads();

    const bool f32 = in_is_fp32(gamma);
    const int nl   = t >> 6;
    const int lane = t & 63;
    const int hq   = lane >> 4;
    const int n    = nb0 + nl;
    const int cnt  = s_cnt[nl];
    const char* tbl = (const char*)hp + (size_t)lane * 8;

    float gv[4], bv[4];
    if (f32) {
        #pragma unroll
        for (int i = 0; i < 4; ++i) {
            gv[i] = ((const float*)gamma)[lane * 4 + i];
            bv[i] = ((const float*)beta)[lane * 4 + i];
        }
    } else {
        #pragma unroll
        for (int i = 0; i < 4; ++i) {
            gv[i] = bf2f(((const unsigned short*)gamma)[lane * 4 + i]);
            bv[i] = bf2f(((const unsigned short*)beta)[lane * 4 + i]);
        }
    }

    floatx2 acc[2];
    acc[0] = (floatx2){0.f, 0.f};
    acc[1] = (floatx2){0.f, 0.f};

    for (int m = 0; m < cnt; m += 4) {
        #pragma unroll
        for (int k = 0; k < 4; ++k) {
            const int   off = s_off[nl][m + k];
            const float aa  = s_al[nl][m + k][hq];
            uintx2 u = *(const uintx2*)(tbl + off);
            #pragma unroll
            for (int j = 0; j < 2; ++j) {
                floatx2 f = { u2f(u[j] << 16), u2f(u[j] & 0xffff0000u) };
                acc[j] += (floatx2){aa, aa} * f;
            }
        }
    }
    {
        uintx2 u = *(const uintx2*)((const char*)hp + (size_t)n * (DIM * 2) + lane * 8);
        #pragma unroll
        for (int j = 0; j < 2; ++j) {
            floatx2 f = { u2f(u[j] << 16), u2f(u[j] & 0xffff0000u) };
            acc[j] += f;
        }
    }

    float x[4], s1 = 0.f, s2 = 0.f;
    #pragma unroll
    for (int j = 0; j < 2; ++j) {
        #pragma unroll
        for (int e = 0; e < 2; ++e) {
            float xi = acc[j][e];
            xi = 0.5f * xi * (1.f + erf_fast(xi * 0.70710678118654752f));
            x[2 * j + e] = xi;
            s1 += xi;
            s2 += xi * xi;
        }
    }
    #pragma unroll
    for (int off = 1; off < 64; off <<= 1) {
        s1 += __shfl_xor(s1, off);
        s2 += __shfl_xor(s2, off);
    }
    const float mu  = s1 * (1.f / 256.f);
    float var = s2 * (1.f / 256.f) - mu * mu;
    var = fmaxf(var, 0.f);
    const float inv = rsqrtf(var + LN_EPS);

    if (f32) {
        floatx4 o;
        #pragma unroll
        for (int i = 0; i < 4; ++i)
            o[i] = (x[i] - mu) * inv * gv[i] + bv[i];
        *(floatx4*)((float*)out + (size_t)n * DIM + lane * 4) = o;
    } else {
        short4v o;
        #pragma unroll
        for (int i = 0; i < 4; ++i)
            o[i] = (short)f2bf((x[i] - mu) * inv * gv[i] + bv[i]);
        *(short4v*)((unsigned short*)out + (size_t)n * DIM + lane * 4) = o;
    }
}

extern "C" void kernel_launch(void* const* d_in, const int* in_sizes, int n_in,
                              void* d_out, int out_size, void* d_ws, size_t ws_size,
                              hipStream_t stream) {
    const void* h     = d_in[0];
    const int*  nidx  = (const int*)d_in[1];
    const int*  nmask = (const int*)d_in[2];
    const void* W     = d_in[3];
    const void* al    = d_in[4];
    const void* ar    = d_in[5];
    const void* gamma = d_in[6];
    const void* beta  = d_in[7];

    unsigned short* hp    = (unsigned short*)d_ws;
    float* el_nh = (float*)((char*)d_ws + 10240000);
    float* er_nh = (float*)((char*)d_ws + 10560000);

    // MEASUREMENT ROUND: replicated/probed dispatches (all named, all clear the
    // ~45us top-5 bar). Probes write garbage ONLY to d_out; the final real
    // k_fuse (last) overwrites every byte of d_out with correct values.
    k_gemm<<<REPL_G * NBLK_G, 256, 0, stream>>>(h, gamma, W, al, ar, hp, el_nh, er_nh);
    k_p1  <<<REPL_P1 * NBLK_F, 256, 0, stream>>>(nidx, nmask, el_nh, er_nh, d_out);
    k_p2  <<<REPL_P2 * NBLK_F, 256, 0, stream>>>(hp, gamma, beta, d_out, 0);  // random rows
    k_p2  <<<REPL_P2 * NBLK_F, 256, 0, stream>>>(hp, gamma, beta, d_out, 1);  // own-row (hot)
    k_fuse<<<REPL_F * NBLK_F, 256, 0, stream>>>(nidx, nmask, hp, el_nh, er_nh,
                                                gamma, beta, d_out);
}

// Round 11
// 131.700 us; speedup vs baseline: 3.3607x; 3.3607x over previous
//
#include <hip/hip_runtime.h>
#include <math.h>

#define N_NODES 20000
#define M_NEI   32
#define DIM     256
#define H_HEADS 4
#define D_HEAD  64
#define LN_EPS  1e-5f
#define NEG_INF -1.0e9f
#define APAD    264         // 256 + 8 halves pad for LDS A tile

using short8  = __attribute__((ext_vector_type(8))) short;
using short4v = __attribute__((ext_vector_type(4))) short;
using floatx4 = __attribute__((ext_vector_type(4))) float;
using floatx2 = __attribute__((ext_vector_type(2))) float;
using uintx4  = __attribute__((ext_vector_type(4))) unsigned int;
using uintx2  = __attribute__((ext_vector_type(2))) unsigned int;

__device__ __forceinline__ float bf2f(unsigned short u) {
    union { unsigned int i; float f; } c; c.i = ((unsigned int)u) << 16; return c.f;
}
__device__ __forceinline__ float u2f(unsigned int i) {
    union { unsigned int i; float f; } c; c.i = i; return c.f;
}
__device__ __forceinline__ unsigned short f2bf(float f) {
    union { float f; unsigned int i; } c; c.f = f;
    unsigned int x = c.i;
    x += 0x7fffu + ((x >> 16) & 1u);          // RNE
    return (unsigned short)(x >> 16);
}
__device__ __forceinline__ bool in_is_fp32(const void* gamma) {
    return *(const unsigned int*)gamma == 0x3F800000u;
}
__device__ __forceinline__ float fast_exp(float x) {
    return __builtin_amdgcn_exp2f(x * 1.44269504088896341f);
}
// A&S 7.1.26 erf (max abs err 1.5e-7); invisible at bf16 output precision.
__device__ __forceinline__ float erf_fast(float x) {
    float ax = fabsf(x);
    float t  = __builtin_amdgcn_rcpf(fmaf(0.3275911f, ax, 1.0f));
    float p  = fmaf(1.061405429f, t, -1.453152027f);
    p = fmaf(p, t, 1.421413741f);
    p = fmaf(p, t, -0.284496736f);
    p = fmaf(p, t, 0.254829592f);
    p = p * t;
    float e  = __builtin_amdgcn_exp2f(-ax * ax * 1.44269504088896341f);
    float r  = fmaf(-p, e, 1.0f);
    return copysignf(r, x);
}

// ---------------- prep: W -> bf16 Wt[n][k] = W[k][n] (coalesced writes) ---------
// Restored (R10 probe: folded scalar B-preload = 41M VMEM instrs, ~5us of g).
__global__ void k_prep(const void* __restrict__ W, const void* __restrict__ gamma,
                       unsigned short* __restrict__ Wt) {
    const bool f32 = in_is_fp32(gamma);
    const int n = blockIdx.x;   // output row (col of W)
    const int k = threadIdx.x;  // output col (row of W)
    float w = f32 ? ((const float*)W)[(size_t)k * DIM + n]
                  : bf2f(((const unsigned short*)W)[(size_t)k * DIM + n]);
    Wt[(size_t)n * DIM + k] = f2bf(w);
}

// ---------------- GEMM: hp_h[4][20000][64] head-major + el/er[4][N] epilogue ----
// 625 blocks x 256 threads (4 waves). Tile = 32 rows x 256 cols; wave = head hd.
// B fragments from Wt via 32 x dwordx4 loads per lane (vs 256 scalar loads).
__global__ __launch_bounds__(256, 2) void k_gemm(const void* __restrict__ A,
                                                 const void* __restrict__ gamma,
                                                 const unsigned short* __restrict__ Bt,
                                                 const void* __restrict__ al,
                                                 const void* __restrict__ ar,
                                                 unsigned short* __restrict__ hp_h,
                                                 float* __restrict__ el_h,
                                                 float* __restrict__ er_h) {
    __shared__ unsigned short sA[32][APAD];
    const bool f32 = in_is_fp32(gamma);
    const int t    = threadIdx.x;
    const int m0   = blockIdx.x * 32;
    const int hd   = t >> 6;          // wave = head
    const int lane = t & 63;
    const int r    = lane & 15;
    const int quad = lane >> 4;
    const int n0   = hd * 64;

    // ---- stage 32x256 A tile (fp32 path: float4 vector loads, R3 fix)
    #pragma unroll
    for (int it = 0; it < 4; ++it) {
        int chunk = it * 256 + t;
        int row   = chunk >> 5;
        int c16   = chunk & 31;
        short8 v;
        if (!f32) {
            v = *(const short8*)((const unsigned short*)A + (size_t)(m0 + row) * DIM + c16 * 8);
        } else {
            const float* ap = (const float*)A + (size_t)(m0 + row) * DIM + c16 * 8;
            floatx4 f0 = *(const floatx4*)ap;
            floatx4 f1 = *(const floatx4*)(ap + 4);
            #pragma unroll
            for (int j = 0; j < 4; ++j) {
                v[j]     = (short)f2bf(f0[j]);
                v[4 + j] = (short)f2bf(f1[j]);
            }
        }
        *(short8*)&sA[row][c16 * 8] = v;
    }
    __syncthreads();

    floatx4 acc[2][4];
    #pragma unroll
    for (int rf = 0; rf < 2; ++rf)
        #pragma unroll
        for (int c = 0; c < 4; ++c) acc[rf][c] = (floatx4){0.f, 0.f, 0.f, 0.f};

    #pragma unroll
    for (int k0 = 0; k0 < DIM; k0 += 32) {
        short8 a0 = *(const short8*)&sA[r][k0 + quad * 8];
        short8 a1 = *(const short8*)&sA[16 + r][k0 + quad * 8];
        #pragma unroll
        for (int c = 0; c < 4; ++c) {
            short8 b = *(const short8*)(Bt + (size_t)(n0 + c * 16 + r) * DIM + k0 + quad * 8);
            acc[0][c] = __builtin_amdgcn_mfma_f32_16x16x32_bf16(a0, b, acc[0][c], 0, 0, 0);
            acc[1][c] = __builtin_amdgcn_mfma_f32_16x16x32_bf16(a1, b, acc[1][c], 0, 0, 0);
        }
    }

    float alv[4], arv[4];
    #pragma unroll
    for (int c = 0; c < 4; ++c) {
        int col = n0 + c * 16 + r;
        if (f32) { alv[c] = ((const float*)al)[col]; arv[c] = ((const float*)ar)[col]; }
        else     { alv[c] = bf2f(((const unsigned short*)al)[col]);
                   arv[c] = bf2f(((const unsigned short*)ar)[col]); }
    }

    // C/D layout: col = lane&15, row = quad*4 + reg  [measured m89/m91]
    #pragma unroll
    for (int rf = 0; rf < 2; ++rf) {
        #pragma unroll
        for (int rr = 0; rr < 4; ++rr) {
            const int row = m0 + rf * 16 + quad * 4 + rr;
            float sl = 0.f, sr = 0.f;
            #pragma unroll
            for (int c = 0; c < 4; ++c) {
                float v = acc[rf][c][rr];
                sl += v * alv[c];
                sr += v * arv[c];
                hp_h[((size_t)hd * N_NODES + row) * D_HEAD + c * 16 + r] = f2bf(v);
            }
            #pragma unroll
            for (int off = 1; off < 16; off <<= 1) {
                sl += __shfl_xor(sl, off);
                sr += __shfl_xor(sr, off);
            }
            if (r == 0) {
                el_h[(size_t)hd * N_NODES + row] = sl;
                er_h[(size_t)hd * N_NODES + row] = sr;
            }
        }
    }
}

// ---------------- head-pinned attention gather + residual -----------------------
// hd = blockIdx&3: with 8 XCDs, head h's blocks land on XCDs {h, h+4} only, so
// each XCD's L2 caches ONE 2.56MB head table (fits 4MB) — R10 probe showed the
// merged 10MB table missed ~40% to HBM (84MB FETCH/pass); this kills that.
// Compaction + 4-deep zero-padded MLP (pads: off=0,alpha=0 -> bitwise no-op).
__global__ __launch_bounds__(256) void k_attn(const int* __restrict__ nidx,
                                              const int* __restrict__ nmask,
                                              const unsigned short* __restrict__ hp_h,
                                              const float* __restrict__ el_h,
                                              const float* __restrict__ er_h,
                                              unsigned short* __restrict__ out_h) {
    __shared__ int2 s_oa[32][33];              // {idx*128, alpha bits}, compacted
    __shared__ int  s_cnt[32];

    const int hd  = blockIdx.x & 3;
    const int nb0 = (blockIdx.x >> 2) * 32;
    const int t   = threadIdx.x;

    // zero all slots (pads must be {0, 0.0f})
    {
        int2* p = &s_oa[0][0];
        for (int i = t; i < 32 * 33; i += 256) p[i] = (int2){0, 0};
    }
    __syncthreads();

    // ---- phase 1: per-head softmax + compaction ----
    {
        const int m   = t & 31;
        const int sub = t >> 5;                 // 0..7
        #pragma unroll
        for (int it = 0; it < 4; ++it) {
            const int nl  = it * 8 + sub;
            const int n   = nb0 + nl;
            const int idx = nidx[(size_t)n * M_NEI + m];
            const int msk = nmask[(size_t)n * M_NEI + m];
            float e = el_h[(size_t)hd * N_NODES + n] + er_h[(size_t)hd * N_NODES + idx];
            e = (e > 0.f) ? e : 0.2f * e;       // leaky_relu(0.2)
            e = msk ? e : NEG_INF;
            float mx = e;
            #pragma unroll
            for (int off = 1; off < 32; off <<= 1) mx = fmaxf(mx, __shfl_xor(mx, off, 32));
            float a = fast_exp(e - mx);
            float sm = a;
            #pragma unroll
            for (int off = 1; off < 32; off <<= 1) sm += __shfl_xor(sm, off, 32);
            a *= __builtin_amdgcn_rcpf(sm);

            unsigned long long bal64 = __ballot(msk != 0);
            unsigned int bal = (t & 32) ? (unsigned int)(bal64 >> 32)
                                        : (unsigned int)bal64;
            int  cnt   = __popc(bal);
            bool valid = (msk != 0);
            if (cnt == 0) { valid = true; cnt = 32; bal = 0xffffffffu; }  // uniform 1/32
            if (valid) {
                int pfx = __popc(bal & ((1u << m) - 1u));
                int2 oa;
                oa.x = idx * (D_HEAD * 2);      // byte offset into head table
                union { float f; int i; } c; c.f = a;
                oa.y = c.i;
                s_oa[nl][pfx] = oa;
            }
            if (m == 0) s_cnt[nl] = cnt;
        }
    }
    __syncthreads();

    // ---- phase 2: 8-lane group per node; lane s owns feats [8s, 8s+8) --------
    const int wave = t >> 6;
    const int lane = t & 63;
    const int g    = lane >> 3;                 // node within wave
    const int s    = lane & 7;                  // feat octet
    const int nl   = wave * 8 + g;
    const int n    = nb0 + nl;
    const int cnt  = s_cnt[nl];
    const char* tbl = (const char*)hp_h + (size_t)hd * N_NODES * (D_HEAD * 2) + s * 16;

    floatx2 acc[4];
    #pragma unroll
    for (int j = 0; j < 4; ++j) acc[j] = (floatx2){0.f, 0.f};

    for (int m = 0; m < cnt; m += 4) {          // 4-deep MLP; pads are bitwise no-ops
        #pragma unroll
        for (int k = 0; k < 4; ++k) {
            const int2  oa = s_oa[nl][m + k];
            const float aa = u2f((unsigned int)oa.y);
            uintx4 u = *(const uintx4*)(tbl + oa.x);
            #pragma unroll
            for (int j = 0; j < 4; ++j) {
                floatx2 f = { u2f(u[j] << 16), u2f(u[j] & 0xffff0000u) };
                acc[j] += (floatx2){aa, aa} * f;    // v_pk_fma_f32
            }
        }
    }

    // residual: + hp_h[hd][n][8s..8s+8)
    {
        uintx4 u = *(const uintx4*)((const char*)hp_h
                     + ((size_t)hd * N_NODES + n) * (D_HEAD * 2) + s * 16);
        #pragma unroll
        for (int j = 0; j < 4; ++j) {
            floatx2 f = { u2f(u[j] << 16), u2f(u[j] & 0xffff0000u) };
            acc[j] += f;
        }
    }

    short8 o;
    #pragma unroll
    for (int j = 0; j < 4; ++j) {
        o[2 * j]     = (short)f2bf(acc[j][0]);
        o[2 * j + 1] = (short)f2bf(acc[j][1]);
    }
    *(short8*)(out_h + ((size_t)hd * N_NODES + n) * D_HEAD + s * 8) = o;
}

// ---------------- GELU + LayerNorm ----------------
// 5000 blocks x 256: one wave per node; lane covers head lane>>4, feats
// ((lane&15)*4 .. +4). erf_fast replaces libm erff.
__global__ __launch_bounds__(256) void k_final(const unsigned short* __restrict__ out_h,
                                               const void* __restrict__ gamma,
                                               const void* __restrict__ beta,
                                               void* __restrict__ out) {
    const bool f32 = in_is_fp32(gamma);
    const int wave = threadIdx.x >> 6;
    const int lane = threadIdx.x & 63;
    const int n    = blockIdx.x * 4 + wave;
    const int h    = lane >> 4;
    const int d0   = (lane & 15) * 4;

    const size_t off = ((size_t)h * N_NODES + n) * D_HEAD + d0;
    short4v ov = *(const short4v*)(out_h + off);

    float x[4], s1 = 0.f, s2 = 0.f;
    #pragma unroll
    for (int i = 0; i < 4; ++i) {
        float xi = bf2f((unsigned short)ov[i]);
        xi = 0.5f * xi * (1.f + erf_fast(xi * 0.70710678118654752f));
        x[i] = xi;
        s1 += xi;
        s2 += xi * xi;
    }
    #pragma unroll
    for (int offv = 1; offv < 64; offv <<= 1) {
        s1 += __shfl_xor(s1, offv);
        s2 += __shfl_xor(s2, offv);
    }
    const float mu  = s1 * (1.f / 256.f);
    float var = s2 * (1.f / 256.f) - mu * mu;
    var = fmaxf(var, 0.f);
    const float inv = rsqrtf(var + LN_EPS);

    // gamma/beta flat index = h*64 + d0 + i = lane*4 + i
    if (f32) {
        const float* gp = (const float*)gamma + lane * 4;
        const float* bp = (const float*)beta  + lane * 4;
        floatx4 o;
        #pragma unroll
        for (int i = 0; i < 4; ++i)
            o[i] = (x[i] - mu) * inv * gp[i] + bp[i];
        *(floatx4*)((float*)out + (size_t)n * DIM + lane * 4) = o;
    } else {
        const unsigned short* gp = (const unsigned short*)gamma + lane * 4;
        const unsigned short* bp = (const unsigned short*)beta  + lane * 4;
        short4v o;
        #pragma unroll
        for (int i = 0; i < 4; ++i) {
            float y = (x[i] - mu) * inv * bf2f(gp[i]) + bf2f(bp[i]);
            o[i] = (short)f2bf(y);
        }
        *(short4v*)((unsigned short*)out + (size_t)n * DIM + lane * 4) = o;
    }
}

extern "C" void kernel_launch(void* const* d_in, const int* in_sizes, int n_in,
                              void* d_out, int out_size, void* d_ws, size_t ws_size,
                              hipStream_t stream) {
    const void* h     = d_in[0];
    const int*  nidx  = (const int*)d_in[1];
    const int*  nmask = (const int*)d_in[2];
    const void* W     = d_in[3];
    const void* al    = d_in[4];
    const void* ar    = d_in[5];
    const void* gamma = d_in[6];
    const void* beta  = d_in[7];

    // ws layout (bytes):
    //   hp_h  : 0          .. 10,240,000   (bf16 [4][20000][64] head-major)
    //   out_h : 10,240,000 .. 20,480,000   (bf16 [4][20000][64])
    //   el_h  : 20,480,000 .. 20,800,000   (fp32 [4][20000])
    //   er_h  : 20,800,000 .. 21,120,000   (fp32 [4][20000])
    //   Wt    : 21,120,000 .. 21,251,072   (bf16 256x256 transposed)
    unsigned short* hp_h  = (unsigned short*)d_ws;
    unsigned short* out_h = (unsigned short*)((char*)d_ws + 10240000);
    float* el_h = (float*)((char*)d_ws + 20480000);
    float* er_h = (float*)((char*)d_ws + 20800000);
    unsigned short* Wt = (unsigned short*)((char*)d_ws + 21120000);

    k_prep <<<DIM, 256, 0, stream>>>(W, gamma, Wt);
    k_gemm <<<N_NODES / 32, 256, 0, stream>>>(h, gamma, Wt, al, ar, hp_h, el_h, er_h);
    k_attn <<<H_HEADS * (N_NODES / 32), 256, 0, stream>>>(nidx, nmask, hp_h, el_h, er_h, out_h);
    k_final<<<N_NODES / 4, 256, 0, stream>>>(out_h, gamma, beta, d_out);
}

// Round 12
// 127.030 us; speedup vs baseline: 3.4842x; 1.0368x over previous
//
#include <hip/hip_runtime.h>
#include <math.h>

#define N_NODES 20000
#define M_NEI   32
#define DIM     256
#define H_HEADS 4
#define D_HEAD  64
#define LN_EPS  1e-5f
#define NEG_INF -1.0e9f
#define APAD    264         // 256 + 8 halves pad for LDS A tile
#define NB      4           // nodes per k_fuse block (4 x 5000 blocks)

using short8  = __attribute__((ext_vector_type(8))) short;
using short4v = __attribute__((ext_vector_type(4))) short;
using floatx4 = __attribute__((ext_vector_type(4))) float;
using floatx2 = __attribute__((ext_vector_type(2))) float;
using uintx4  = __attribute__((ext_vector_type(4))) unsigned int;
using uintx2  = __attribute__((ext_vector_type(2))) unsigned int;

__device__ __forceinline__ float bf2f(unsigned short u) {
    union { unsigned int i; float f; } c; c.i = ((unsigned int)u) << 16; return c.f;
}
__device__ __forceinline__ float u2f(unsigned int i) {
    union { unsigned int i; float f; } c; c.i = i; return c.f;
}
__device__ __forceinline__ unsigned short f2bf(float f) {
    union { float f; unsigned int i; } c; c.f = f;
    unsigned int x = c.i;
    x += 0x7fffu + ((x >> 16) & 1u);          // RNE
    return (unsigned short)(x >> 16);
}
__device__ __forceinline__ bool in_is_fp32(const void* gamma) {
    return *(const unsigned int*)gamma == 0x3F800000u;
}
__device__ __forceinline__ float fast_exp(float x) {
    return __builtin_amdgcn_exp2f(x * 1.44269504088896341f);
}
// A&S 7.1.26 erf (max abs err 1.5e-7); invisible at bf16 output precision.
__device__ __forceinline__ float erf_fast(float x) {
    float ax = fabsf(x);
    float t  = __builtin_amdgcn_rcpf(fmaf(0.3275911f, ax, 1.0f));
    float p  = fmaf(1.061405429f, t, -1.453152027f);
    p = fmaf(p, t, 1.421413741f);
    p = fmaf(p, t, -0.284496736f);
    p = fmaf(p, t, 0.254829592f);
    p = p * t;
    float e  = __builtin_amdgcn_exp2f(-ax * ax * 1.44269504088896341f);
    float r  = fmaf(-p, e, 1.0f);
    return copysignf(r, x);
}

// ---------------- prep: W -> bf16 Wt[n][k] = W[k][n] (coalesced writes) ---------
// Removes k_gemm's folded scalar B-preload (41M 2-byte VMEM instrs, ~4-5us of g).
__global__ void k_prep(const void* __restrict__ W, const void* __restrict__ gamma,
                       unsigned short* __restrict__ Wt) {
    const bool f32 = in_is_fp32(gamma);
    const int n = blockIdx.x;   // output row (col of W)
    const int k = threadIdx.x;  // output col (row of W)
    float w = f32 ? ((const float*)W)[(size_t)k * DIM + n]
                  : bf2f(((const unsigned short*)W)[(size_t)k * DIM + n]);
    Wt[(size_t)n * DIM + k] = f2bf(w);
}

// ---------------- GEMM: hp[n][256] row-major + el/er[n][4] epilogue -------------
// 625 blocks x 256 threads (4 waves). Tile = 32 rows x 256 cols; wave = head hd.
// B fragments from Wt via 32 x dwordx4 loads per lane. Output bit-identical
// to the round-9 kernel (same RNE conversions, same MFMA order).
__global__ __launch_bounds__(256, 2) void k_gemm(const void* __restrict__ A,
                                                 const void* __restrict__ gamma,
                                                 const unsigned short* __restrict__ Bt,
                                                 const void* __restrict__ al,
                                                 const void* __restrict__ ar,
                                                 unsigned short* __restrict__ hp,
                                                 float* __restrict__ el_nh,
                                                 float* __restrict__ er_nh) {
    __shared__ unsigned short sA[32][APAD];
    const bool f32 = in_is_fp32(gamma);
    const int t    = threadIdx.x;
    const int m0   = blockIdx.x * 32;
    const int hd   = t >> 6;          // wave = head
    const int lane = t & 63;
    const int r    = lane & 15;
    const int quad = lane >> 4;
    const int n0   = hd * 64;

    // ---- stage 32x256 A tile (fp32 path: float4 vector loads)
    #pragma unroll
    for (int it = 0; it < 4; ++it) {
        int chunk = it * 256 + t;
        int row   = chunk >> 5;
        int c16   = chunk & 31;
        short8 v;
        if (!f32) {
            v = *(const short8*)((const unsigned short*)A + (size_t)(m0 + row) * DIM + c16 * 8);
        } else {
            const float* ap = (const float*)A + (size_t)(m0 + row) * DIM + c16 * 8;
            floatx4 f0 = *(const floatx4*)ap;
            floatx4 f1 = *(const floatx4*)(ap + 4);
            #pragma unroll
            for (int j = 0; j < 4; ++j) {
                v[j]     = (short)f2bf(f0[j]);
                v[4 + j] = (short)f2bf(f1[j]);
            }
        }
        *(short8*)&sA[row][c16 * 8] = v;
    }
    __syncthreads();

    floatx4 acc[2][4];
    #pragma unroll
    for (int rf = 0; rf < 2; ++rf)
        #pragma unroll
        for (int c = 0; c < 4; ++c) acc[rf][c] = (floatx4){0.f, 0.f, 0.f, 0.f};

    #pragma unroll
    for (int k0 = 0; k0 < DIM; k0 += 32) {
        short8 a0 = *(const short8*)&sA[r][k0 + quad * 8];
        short8 a1 = *(const short8*)&sA[16 + r][k0 + quad * 8];
        #pragma unroll
        for (int c = 0; c < 4; ++c) {
            short8 b = *(const short8*)(Bt + (size_t)(n0 + c * 16 + r) * DIM + k0 + quad * 8);
            acc[0][c] = __builtin_amdgcn_mfma_f32_16x16x32_bf16(a0, b, acc[0][c], 0, 0, 0);
            acc[1][c] = __builtin_amdgcn_mfma_f32_16x16x32_bf16(a1, b, acc[1][c], 0, 0, 0);
        }
    }

    float alv[4], arv[4];
    #pragma unroll
    for (int c = 0; c < 4; ++c) {
        int col = n0 + c * 16 + r;
        if (f32) { alv[c] = ((const float*)al)[col]; arv[c] = ((const float*)ar)[col]; }
        else     { alv[c] = bf2f(((const unsigned short*)al)[col]);
                   arv[c] = bf2f(((const unsigned short*)ar)[col]); }
    }

    // C/D layout: col = lane&15, row = quad*4 + reg  [measured m89/m91]
    #pragma unroll
    for (int rf = 0; rf < 2; ++rf) {
        #pragma unroll
        for (int rr = 0; rr < 4; ++rr) {
            const int row = m0 + rf * 16 + quad * 4 + rr;
            float sl = 0.f, sr = 0.f;
            #pragma unroll
            for (int c = 0; c < 4; ++c) {
                float v = acc[rf][c][rr];
                sl += v * alv[c];
                sr += v * arv[c];
                hp[(size_t)row * DIM + n0 + c * 16 + r] = f2bf(v);   // row-major
            }
            #pragma unroll
            for (int off = 1; off < 16; off <<= 1) {
                sl += __shfl_xor(sl, off);
                sr += __shfl_xor(sr, off);
            }
            if (r == 0) {
                el_nh[(size_t)row * H_HEADS + hd] = sl;
                er_nh[(size_t)row * H_HEADS + hd] = sr;
            }
        }
    }
}

// ---------------- fused attention (all heads) + residual + GELU + LayerNorm ----
// Round-9 kernel verbatim (best measured: its structure beat R11's head-split
// by 5.5us). NB=4 nodes/block x 5000 blocks.
__global__ __launch_bounds__(256) void k_fuse(const int* __restrict__ nidx,
                                              const int* __restrict__ nmask,
                                              const unsigned short* __restrict__ hp,
                                              const float* __restrict__ el_nh,
                                              const float* __restrict__ er_nh,
                                              const void* __restrict__ gamma,
                                              const void* __restrict__ beta,
                                              void* __restrict__ out) {
    __shared__ int   s_off[NB][33];
    __shared__ float s_al[NB][33][4];
    __shared__ int   s_cnt[NB];

    const int t   = threadIdx.x;
    const int nb0 = blockIdx.x * NB;

    // zero compaction slots (padded entries must be {0, 0,0,0,0}); NB*33 = 132
    {
        int*     offp = &s_off[0][0];
        floatx4* alp  = (floatx4*)&s_al[0][0][0];
        if (t < NB * 33) {
            offp[t] = 0;
            alp[t]  = (floatx4){0.f, 0.f, 0.f, 0.f};
        }
    }
    __syncthreads();

    // ---- phase 1: 4-head softmax + compaction (threads 0..127) ----
    if (t < NB * 32) {
        const int m   = t & 31;
        const int nl  = t >> 5;                 // 0..3
        const int n   = nb0 + nl;
        const int idx = nidx[(size_t)n * M_NEI + m];
        const int msk = nmask[(size_t)n * M_NEI + m];
        floatx4 el4 = *(const floatx4*)(el_nh + (size_t)n * H_HEADS);
        floatx4 er4 = *(const floatx4*)(er_nh + (size_t)idx * H_HEADS);
        floatx4 e4, a4;
        #pragma unroll
        for (int hh = 0; hh < 4; ++hh) {
            float e = el4[hh] + er4[hh];
            e = (e > 0.f) ? e : 0.2f * e;       // leaky_relu(0.2)
            e4[hh] = msk ? e : NEG_INF;
        }
        floatx4 mx = e4;
        #pragma unroll
        for (int off = 1; off < 32; off <<= 1)
            #pragma unroll
            for (int hh = 0; hh < 4; ++hh)
                mx[hh] = fmaxf(mx[hh], __shfl_xor(mx[hh], off, 32));
        #pragma unroll
        for (int hh = 0; hh < 4; ++hh) a4[hh] = fast_exp(e4[hh] - mx[hh]);
        floatx4 sm = a4;
        #pragma unroll
        for (int off = 1; off < 32; off <<= 1)
            #pragma unroll
            for (int hh = 0; hh < 4; ++hh)
                sm[hh] += __shfl_xor(sm[hh], off, 32);
        #pragma unroll
        for (int hh = 0; hh < 4; ++hh) a4[hh] *= __builtin_amdgcn_rcpf(sm[hh]);

        // compaction (mask is head-independent; group = 32 lanes of wave 0/1)
        unsigned long long bal64 = __ballot(msk != 0);
        unsigned int bal = (t & 32) ? (unsigned int)(bal64 >> 32)
                                    : (unsigned int)bal64;
        int  cnt   = __popc(bal);
        bool valid = (msk != 0);
        if (cnt == 0) { valid = true; cnt = 32; bal = 0xffffffffu; }  // uniform 1/32
        if (valid) {
            int pfx = __popc(bal & ((1u << m) - 1u));
            s_off[nl][pfx] = idx * (DIM * 2);          // byte offset of 512B row
            *(floatx4*)&s_al[nl][pfx][0] = a4;
        }
        if (m == 0) s_cnt[nl] = cnt;
    }
    __syncthreads();

    // ---- phase 2: one node per 64-lane wave; lane = 4 feats [lane*4, lane*4+4)
    const bool f32 = in_is_fp32(gamma);
    const int nl   = t >> 6;                    // wave = node 0..3
    const int lane = t & 63;
    const int hq   = lane >> 4;                 // head for alpha lookup
    const int n    = nb0 + nl;
    const int cnt  = s_cnt[nl];
    const char* tbl = (const char*)hp + (size_t)lane * 8;

    float gv[4], bv[4];
    if (f32) {
        #pragma unroll
        for (int i = 0; i < 4; ++i) {
            gv[i] = ((const float*)gamma)[lane * 4 + i];
            bv[i] = ((const float*)beta)[lane * 4 + i];
        }
    } else {
        #pragma unroll
        for (int i = 0; i < 4; ++i) {
            gv[i] = bf2f(((const unsigned short*)gamma)[lane * 4 + i]);
            bv[i] = bf2f(((const unsigned short*)beta)[lane * 4 + i]);
        }
    }

    floatx2 acc[2];
    acc[0] = (floatx2){0.f, 0.f};
    acc[1] = (floatx2){0.f, 0.f};

    for (int m = 0; m < cnt; m += 4) {          // 4-deep MLP; pads are bitwise no-ops
        #pragma unroll
        for (int k = 0; k < 4; ++k) {
            const int   off = s_off[nl][m + k];
            const float aa  = s_al[nl][m + k][hq];
            uintx2 u = *(const uintx2*)(tbl + off);
            #pragma unroll
            for (int j = 0; j < 2; ++j) {
                floatx2 f = { u2f(u[j] << 16), u2f(u[j] & 0xffff0000u) };
                acc[j] += (floatx2){aa, aa} * f;    // v_pk_fma_f32
            }
        }
    }

    // residual: + hp[n][lane*4 .. +4)
    {
        uintx2 u = *(const uintx2*)((const char*)hp + (size_t)n * (DIM * 2) + lane * 8);
        #pragma unroll
        for (int j = 0; j < 2; ++j) {
            floatx2 f = { u2f(u[j] << 16), u2f(u[j] & 0xffff0000u) };
            acc[j] += f;
        }
    }

    // fast-erf GELU + LayerNorm (64-lane butterfly covers all 256 feats)
    float x[4], s1 = 0.f, s2 = 0.f;
    #pragma unroll
    for (int j = 0; j < 2; ++j) {
        #pragma unroll
        for (int e = 0; e < 2; ++e) {
            float xi = acc[j][e];
            xi = 0.5f * xi * (1.f + erf_fast(xi * 0.70710678118654752f));
            x[2 * j + e] = xi;
            s1 += xi;
            s2 += xi * xi;
        }
    }
    #pragma unroll
    for (int off = 1; off < 64; off <<= 1) {
        s1 += __shfl_xor(s1, off);
        s2 += __shfl_xor(s2, off);
    }
    const float mu  = s1 * (1.f / 256.f);
    float var = s2 * (1.f / 256.f) - mu * mu;
    var = fmaxf(var, 0.f);
    const float inv = rsqrtf(var + LN_EPS);

    if (f32) {
        floatx4 o;
        #pragma unroll
        for (int i = 0; i < 4; ++i)
            o[i] = (x[i] - mu) * inv * gv[i] + bv[i];
        *(floatx4*)((float*)out + (size_t)n * DIM + lane * 4) = o;
    } else {
        short4v o;
        #pragma unroll
        for (int i = 0; i < 4; ++i)
            o[i] = (short)f2bf((x[i] - mu) * inv * gv[i] + bv[i]);
        *(short4v*)((unsigned short*)out + (size_t)n * DIM + lane * 4) = o;
    }
}

extern "C" void kernel_launch(void* const* d_in, const int* in_sizes, int n_in,
                              void* d_out, int out_size, void* d_ws, size_t ws_size,
                              hipStream_t stream) {
    const void* h     = d_in[0];
    const int*  nidx  = (const int*)d_in[1];
    const int*  nmask = (const int*)d_in[2];
    const void* W     = d_in[3];
    const void* al    = d_in[4];
    const void* ar    = d_in[5];
    const void* gamma = d_in[6];
    const void* beta  = d_in[7];

    // ws layout (bytes):
    //   hp    : 0          .. 10,240,000   (bf16 [20000][256] row-major)
    //   el_nh : 10,240,000 .. 10,560,000   (fp32 [20000][4])
    //   er_nh : 10,560,000 .. 10,880,000   (fp32 [20000][4])
    //   Wt    : 10,880,000 .. 11,011,072   (bf16 256x256 transposed)
    unsigned short* hp    = (unsigned short*)d_ws;
    float* el_nh = (float*)((char*)d_ws + 10240000);
    float* er_nh = (float*)((char*)d_ws + 10560000);
    unsigned short* Wt = (unsigned short*)((char*)d_ws + 10880000);

    k_prep<<<DIM, 256, 0, stream>>>(W, gamma, Wt);
    k_gemm<<<N_NODES / 32, 256, 0, stream>>>(h, gamma, Wt, al, ar, hp, el_nh, er_nh);
    k_fuse<<<N_NODES / NB, 256, 0, stream>>>(nidx, nmask, hp, el_nh, er_nh,
                                             gamma, beta, d_out);
}